// Round 9
// baseline (212.033 us; speedup 1.0000x reference)
//
#include <hip/hip_runtime.h>
#include <hip/hip_bf16.h>
#include <stdint.h>

using u16 = unsigned short;

typedef __attribute__((ext_vector_type(8))) short bf16x8;
typedef __attribute__((ext_vector_type(4))) float f32x4;

typedef const __attribute__((address_space(1))) unsigned int* gas_t;
typedef __attribute__((address_space(3))) unsigned int* las_t;

__device__ inline void g2l16(const u16* g, u16* l) {
  __builtin_amdgcn_global_load_lds((gas_t)g, (las_t)l, 16, 0, 0);
}

__device__ inline u16 f2b(float x) {
  union { float f; uint32_t u; } v; v.f = x;
  uint32_t r = (v.u + 0x7FFFu + ((v.u >> 16) & 1u)) >> 16;
  return (u16)r;
}
__device__ inline float b2f(u16 b) {
  union { uint32_t u; float f; } v; v.u = ((uint32_t)b) << 16;
  return v.f;
}
__device__ inline float b2f_lo(uint32_t p) {
  union { uint32_t u; float f; } v; v.u = p << 16; return v.f;
}
__device__ inline float b2f_hi(uint32_t p) {
  union { uint32_t u; float f; } v; v.u = p & 0xFFFF0000u; return v.f;
}

__device__ inline void store_out(float* p, float v) { *p = v; }
__device__ inline void store_out(u16* p, float v) { *p = f2b(v); }

// ---------------------------------------------------------------------------
// Core 128x128 GEMM tile. BK=64, XOR-swizzled LDS (0 conflicts, verified R3).
// ---------------------------------------------------------------------------
template<typename OutT>
__device__ inline void gemm_tile_128(const u16* __restrict__ A,
                                     const u16* __restrict__ Bt,
                                     const float* __restrict__ bias,
                                     OutT* __restrict__ C,
                                     int m0, int n0, int N, int K,
                                     u16* As, u16* Bs)
{
  const int tid  = threadIdx.x;
  const int wave = tid >> 6;
  const int lane = tid & 63;
  const int wm = wave >> 1, wn = wave & 1;
  const int lr = lane & 15;
  const int lq = lane >> 4;
  const int x7 = lr & 7;

  const int srow = tid >> 3;
  const int sgc  = (tid & 7) ^ (srow & 7);
  const u16* gA = A  + (size_t)(m0 + srow) * K + sgc * 8;
  const u16* gB = Bt + (size_t)(n0 + srow) * K + sgc * 8;
  u16* dstA = As + wave * 512;
  u16* dstB = Bs + wave * 512;

  f32x4 acc[4][4];
  #pragma unroll
  for (int i = 0; i < 4; ++i)
    #pragma unroll
    for (int j = 0; j < 4; ++j)
      acc[i][j] = (f32x4){0.f, 0.f, 0.f, 0.f};

  for (int k0 = 0; k0 < K; k0 += 64) {
    #pragma unroll
    for (int s = 0; s < 4; ++s) {
      g2l16(gA + (size_t)(s * 32) * K + k0, dstA + s * 2048);
      g2l16(gB + (size_t)(s * 32) * K + k0, dstB + s * 2048);
    }
    __syncthreads();

    #pragma unroll
    for (int ks = 0; ks < 2; ++ks) {
      const int pa = (ks * 4 + lq) ^ x7;
      bf16x8 af[4], bfr[4];
      #pragma unroll
      for (int im = 0; im < 4; ++im)
        af[im] = *(const bf16x8*)&As[(wm * 64 + im * 16 + lr) * 64 + pa * 8];
      #pragma unroll
      for (int in = 0; in < 4; ++in)
        bfr[in] = *(const bf16x8*)&Bs[(wn * 64 + in * 16 + lr) * 64 + pa * 8];

      #pragma unroll
      for (int im = 0; im < 4; ++im)
        #pragma unroll
        for (int in = 0; in < 4; ++in)
          acc[im][in] = __builtin_amdgcn_mfma_f32_16x16x32_bf16(
              af[im], bfr[in], acc[im][in], 0, 0, 0);
    }
    __syncthreads();
  }

  #pragma unroll
  for (int im = 0; im < 4; ++im) {
    const int mbase = m0 + wm * 64 + im * 16 + lq * 4;
    #pragma unroll
    for (int in = 0; in < 4; ++in) {
      const int ncol = n0 + wn * 64 + in * 16 + lr;
      #pragma unroll
      for (int r = 0; r < 4; ++r) {
        const int m = mbase + r;
        store_out(C + (size_t)m * N + ncol, acc[im][in][r] + bias[m]);
      }
    }
  }
}

// keys [4096x4096] (by<32) and Q [1024x4096] (by>=32) in one dispatch.
__global__ __launch_bounds__(256)
void gemm_keys_q(const u16* __restrict__ WIb, const u16* __restrict__ IT,
                 const float* __restrict__ bim, u16* __restrict__ KEYS,
                 const u16* __restrict__ WLb, const u16* __restrict__ PT,
                 const float* __restrict__ bL, u16* __restrict__ Qb)
{
  __shared__ u16 As[128 * 64];
  __shared__ u16 Bs[128 * 64];
  const int by = blockIdx.y;
  const bool keys = (by < 32);
  const u16*   A    = keys ? WIb : WLb;
  const u16*   Bt   = keys ? IT  : PT;
  const float* bias = keys ? bim : bL;
  u16*         C    = keys ? KEYS : Qb;
  const int m0 = (by & 31) * 128;
  const int n0 = blockIdx.x * 128;
  gemm_tile_128<u16>(A, Bt, bias, C, m0, n0, 4096, 1024, As, Bs);
}

// ---------------------------------------------------------------------------
// 64x128 tile GEMM for the final fp32 GEMM (512 blocks). BK=64, swizzled.
// ---------------------------------------------------------------------------
template<typename OutT>
__global__ __launch_bounds__(256)
void gemm_bt_64(const u16* __restrict__ A, const u16* __restrict__ Bt,
                const float* __restrict__ bias, OutT* __restrict__ C,
                int M, int N, int K)
{
  __shared__ u16 As[64 * 64];
  __shared__ u16 Bs[128 * 64];

  const int tid  = threadIdx.x;
  const int wave = tid >> 6;
  const int lane = tid & 63;
  const int lr = lane & 15;
  const int lq = lane >> 4;
  const int x7 = lr & 7;

  const int m0 = blockIdx.y * 64;
  const int n0 = blockIdx.x * 128;

  const int srow = tid >> 3;
  const int sgc  = (tid & 7) ^ (srow & 7);
  const u16* gA = A  + (size_t)(m0 + srow) * K + sgc * 8;
  const u16* gB = Bt + (size_t)(n0 + srow) * K + sgc * 8;
  u16* dstA = As + wave * 512;
  u16* dstB = Bs + wave * 512;

  f32x4 acc[4][2];
  #pragma unroll
  for (int i = 0; i < 4; ++i)
    #pragma unroll
    for (int j = 0; j < 2; ++j)
      acc[i][j] = (f32x4){0.f, 0.f, 0.f, 0.f};

  for (int k0 = 0; k0 < K; k0 += 64) {
    #pragma unroll
    for (int s = 0; s < 2; ++s)
      g2l16(gA + (size_t)(s * 32) * K + k0, dstA + s * 2048);
    #pragma unroll
    for (int s = 0; s < 4; ++s)
      g2l16(gB + (size_t)(s * 32) * K + k0, dstB + s * 2048);
    __syncthreads();

    #pragma unroll
    for (int ks = 0; ks < 2; ++ks) {
      const int pa = (ks * 4 + lq) ^ x7;
      bf16x8 af[4], bfr[2];
      #pragma unroll
      for (int im = 0; im < 4; ++im)
        af[im] = *(const bf16x8*)&As[(im * 16 + lr) * 64 + pa * 8];
      #pragma unroll
      for (int in = 0; in < 2; ++in)
        bfr[in] = *(const bf16x8*)&Bs[(wave * 32 + in * 16 + lr) * 64 + pa * 8];

      #pragma unroll
      for (int im = 0; im < 4; ++im)
        #pragma unroll
        for (int in = 0; in < 2; ++in)
          acc[im][in] = __builtin_amdgcn_mfma_f32_16x16x32_bf16(
              af[im], bfr[in], acc[im][in], 0, 0, 0);
    }
    __syncthreads();
  }

  #pragma unroll
  for (int im = 0; im < 4; ++im) {
    const int mbase = m0 + im * 16 + lq * 4;
    #pragma unroll
    for (int in = 0; in < 2; ++in) {
      const int ncol = n0 + wave * 32 + in * 16 + lr;
      #pragma unroll
      for (int r = 0; r < 4; ++r) {
        const int m = mbase + r;
        store_out(C + (size_t)m * N + ncol, acc[im][in][r] + bias[m]);
      }
    }
  }
}

// ---------------------------------------------------------------------------
// 64x64 vectorized transpose tiles: register 4x4 transpose + LDS b64 ops.
// LDS T stride 68 u16 -> uniform 4-way bank aliasing (= b64 traffic minimum).
// ---------------------------------------------------------------------------
__device__ inline void transpose_tile_f32(const float* __restrict__ in,
                                          u16* __restrict__ out,
                                          int R, int C, int r0, int c0)
{
  __shared__ u16 T[64 * 68];
  const int tr = (threadIdx.x >> 4) * 4;   // row-group base 0..60
  const int tc = (threadIdx.x & 15) * 4;   // col-group base 0..60
  float4 v[4];
  #pragma unroll
  for (int i = 0; i < 4; ++i)
    v[i] = *(const float4*)&in[(size_t)(r0 + tr + i) * C + c0 + tc];
  #pragma unroll
  for (int j = 0; j < 4; ++j) {
    ushort4 o;
    o.x = f2b(((const float*)&v[0])[j]);
    o.y = f2b(((const float*)&v[1])[j]);
    o.z = f2b(((const float*)&v[2])[j]);
    o.w = f2b(((const float*)&v[3])[j]);
    *(ushort4*)&T[(tc + j) * 68 + tr] = o;   // ds_write_b64
  }
  __syncthreads();
  #pragma unroll
  for (int j = 0; j < 4; ++j) {
    const ushort4 o = *(const ushort4*)&T[(tr + j) * 68 + tc];  // ds_read_b64
    *(ushort4*)&out[(size_t)(c0 + tr + j) * R + r0 + tc] = o;
  }
}

__device__ inline void transpose_tile_u16(const u16* __restrict__ in,
                                          u16* __restrict__ out,
                                          int R, int C, int r0, int c0)
{
  __shared__ u16 T[64 * 68];
  const int tr = (threadIdx.x >> 4) * 4;
  const int tc = (threadIdx.x & 15) * 4;
  ushort4 v[4];
  #pragma unroll
  for (int i = 0; i < 4; ++i)
    v[i] = *(const ushort4*)&in[(size_t)(r0 + tr + i) * C + c0 + tc];
  #pragma unroll
  for (int j = 0; j < 4; ++j) {
    ushort4 o;
    o.x = ((const u16*)&v[0])[j];
    o.y = ((const u16*)&v[1])[j];
    o.z = ((const u16*)&v[2])[j];
    o.w = ((const u16*)&v[3])[j];
    *(ushort4*)&T[(tc + j) * 68 + tr] = o;
  }
  __syncthreads();
  #pragma unroll
  for (int j = 0; j < 4; ++j) {
    const ushort4 o = *(const ushort4*)&T[(tr + j) * 68 + tc];
    *(ushort4*)&out[(size_t)(c0 + tr + j) * R + r0 + tc] = o;
  }
}

// ---------------------------------------------------------------------------
// Prep: P,I fp32->bf16 transposed + 3 weight casts + SCORE zero, one dispatch.
// blocks [0,2048): transposes; [2048,8192): weight casts; [8192,8208): zero.
// ---------------------------------------------------------------------------
__global__ __launch_bounds__(256)
void prep(const float* __restrict__ P, u16* __restrict__ PT,
          const float* __restrict__ I, u16* __restrict__ IT,
          const float4* __restrict__ wim, const float4* __restrict__ wl,
          const float4* __restrict__ wf, ushort4* __restrict__ wimb,
          ushort4* __restrict__ wlb, ushort4* __restrict__ wfb,
          float4* __restrict__ score0)
{
  const int bid = blockIdx.x;
  if (bid < 2048) {
    const int z   = bid >> 10;          // 0: P, 1: I
    const int rem = bid & 1023;
    const int c0  = (rem & 63) * 64;    // 64 col-tiles
    const int r0  = (rem >> 6) * 64;    // 16 row-tiles
    transpose_tile_f32(z ? I : P, z ? IT : PT, 1024, 4096, r0, c0);
  } else if (bid < 8192) {
    int i = (bid - 2048) * 256 + threadIdx.x;
    const float4* src; ushort4* dst;
    if (i < 1048576)      { src = wim; dst = wimb; }
    else if (i < 1310720) { src = wl;  dst = wlb;  i -= 1048576; }
    else                  { src = wf;  dst = wfb;  i -= 1310720; }
    const float4 v = src[i];
    ushort4 o;
    o.x = f2b(v.x); o.y = f2b(v.y); o.z = f2b(v.z); o.w = f2b(v.w);
    dst[i] = o;
  } else {
    const int i = (bid - 8192) * 256 + threadIdx.x;   // 4096 float4 = 64 KB
    score0[i] = (float4){0.f, 0.f, 0.f, 0.f};
  }
}

// bf16 [1024 x 4096] -> bf16 [4096 x 1024], 1024 tiles of 64x64
__global__ __launch_bounds__(256)
void transpose_u16(const u16* __restrict__ in, u16* __restrict__ out)
{
  const int c0 = (blockIdx.x & 63) * 64;
  const int r0 = (blockIdx.x >> 6) * 64;
  transpose_tile_u16(in, out, 1024, 4096, r0, c0);
}

// score[h][n] += (1/32)*sum_{c in 16-chunk} Q[c][n]*keys[h*1024+c][n]
// 2 n's per thread via uint loads; grid (8, 64) = 512 blocks; no unroll.
__global__ __launch_bounds__(256)
void score_partial(const u16* __restrict__ keys, const u16* __restrict__ Qb,
                   float* __restrict__ score)
{
  const int n  = (blockIdx.x * 256 + threadIdx.x) * 2;
  const int c0 = blockIdx.y * 16;
  float s0[4] = {0.f, 0.f, 0.f, 0.f};
  float s1[4] = {0.f, 0.f, 0.f, 0.f};
  for (int c = c0; c < c0 + 16; ++c) {
    const uint32_t qv = *(const uint32_t*)&Qb[(size_t)c * 4096 + n];
    const float q0 = b2f_lo(qv), q1 = b2f_hi(qv);
    #pragma unroll
    for (int h = 0; h < 4; ++h) {
      const uint32_t kv = *(const uint32_t*)&keys[((size_t)((h << 10) + c)) * 4096 + n];
      s0[h] = fmaf(q0, b2f_lo(kv), s0[h]);
      s1[h] = fmaf(q1, b2f_hi(kv), s1[h]);
    }
  }
  #pragma unroll
  for (int h = 0; h < 4; ++h) {
    atomicAdd(&score[h * 4096 + n],     s0[h] * 0.03125f);
    atomicAdd(&score[h * 4096 + n + 1], s1[h] * 0.03125f);
  }
}

// softmax over 4 heads -> weightmap
__global__ __launch_bounds__(256)
void softmax_h(const float* __restrict__ score, float* __restrict__ wmap)
{
  const int n = blockIdx.x * 256 + threadIdx.x;
  const float s0 = score[n], s1 = score[4096 + n];
  const float s2 = score[8192 + n], s3 = score[12288 + n];
  const float m = fmaxf(fmaxf(s0, s1), fmaxf(s2, s3));
  const float e0 = expf(s0 - m), e1 = expf(s1 - m);
  const float e2 = expf(s2 - m), e3 = expf(s3 - m);
  const float inv = 1.f / (e0 + e1 + e2 + e3);
  wmap[n] = e0 * inv; wmap[4096 + n] = e1 * inv;
  wmap[8192 + n] = e2 * inv; wmap[12288 + n] = e3 * inv;
}

// z = sum_h w[h][n]*keys[h][c][n]; t = z + Q; LayerNorm over n; bf16 out.
// 8 n's per thread: uint4 (16B) loads on Qb/keys, float4 on w/g/b.
__global__ __launch_bounds__(256)
void z_ln(const u16* __restrict__ keys, const u16* __restrict__ Qb,
          const float* __restrict__ w, const float* __restrict__ g,
          const float* __restrict__ bb, u16* __restrict__ fused)
{
  const int c  = blockIdx.x;
  const int tx = threadIdx.x;
  float t[16];
  float s = 0.f, s2 = 0.f;
  #pragma unroll
  for (int j = 0; j < 2; ++j) {
    const int n = tx * 8 + j * 2048;
    const uint4 qv = *(const uint4*)&Qb[(size_t)c * 4096 + n];
    float z[8] = {0.f,0.f,0.f,0.f,0.f,0.f,0.f,0.f};
    #pragma unroll
    for (int h = 0; h < 4; ++h) {
      const uint4 kv = *(const uint4*)&keys[((size_t)((h << 10) + c)) * 4096 + n];
      const float4 w0 = *(const float4*)&w[h * 4096 + n];
      const float4 w1 = *(const float4*)&w[h * 4096 + n + 4];
      z[0] = fmaf(w0.x, b2f_lo(kv.x), z[0]);
      z[1] = fmaf(w0.y, b2f_hi(kv.x), z[1]);
      z[2] = fmaf(w0.z, b2f_lo(kv.y), z[2]);
      z[3] = fmaf(w0.w, b2f_hi(kv.y), z[3]);
      z[4] = fmaf(w1.x, b2f_lo(kv.z), z[4]);
      z[5] = fmaf(w1.y, b2f_hi(kv.z), z[5]);
      z[6] = fmaf(w1.z, b2f_lo(kv.w), z[6]);
      z[7] = fmaf(w1.w, b2f_hi(kv.w), z[7]);
    }
    const uint32_t qs[4] = {qv.x, qv.y, qv.z, qv.w};
    #pragma unroll
    for (int e = 0; e < 4; ++e) {
      const float v0 = z[2 * e]     + b2f_lo(qs[e]);
      const float v1 = z[2 * e + 1] + b2f_hi(qs[e]);
      t[8 * j + 2 * e]     = v0;
      t[8 * j + 2 * e + 1] = v1;
      s += v0 + v1;
      s2 = fmaf(v0, v0, fmaf(v1, v1, s2));
    }
  }
  #pragma unroll
  for (int o = 32; o > 0; o >>= 1) {
    s  += __shfl_down(s, o);
    s2 += __shfl_down(s2, o);
  }
  __shared__ float rbuf[8];
  const int wave = tx >> 6, lane = tx & 63;
  if (lane == 0) { rbuf[wave] = s; rbuf[4 + wave] = s2; }
  __syncthreads();
  s  = rbuf[0] + rbuf[1] + rbuf[2] + rbuf[3];
  s2 = rbuf[4] + rbuf[5] + rbuf[6] + rbuf[7];
  const float mu  = s * (1.f / 4096.f);
  const float var = s2 * (1.f / 4096.f) - mu * mu;
  const float rs  = rsqrtf(var + 1e-5f);
  #pragma unroll
  for (int j = 0; j < 2; ++j) {
    const int n = tx * 8 + j * 2048;
    #pragma unroll
    for (int q4 = 0; q4 < 2; ++q4) {
      const float4 gv = *(const float4*)&g[n + 4 * q4];
      const float4 bv = *(const float4*)&bb[n + 4 * q4];
      ushort4 o;
      o.x = f2b((t[8 * j + 4 * q4]     - mu) * rs * gv.x + bv.x);
      o.y = f2b((t[8 * j + 4 * q4 + 1] - mu) * rs * gv.y + bv.y);
      o.z = f2b((t[8 * j + 4 * q4 + 2] - mu) * rs * gv.z + bv.z);
      o.w = f2b((t[8 * j + 4 * q4 + 3] - mu) * rs * gv.w + bv.w);
      *(ushort4*)&fused[(size_t)c * 4096 + n + 4 * q4] = o;
    }
  }
}

extern "C" void kernel_launch(void* const* d_in, const int* in_sizes, int n_in,
                              void* d_out, int out_size, void* d_ws, size_t ws_size,
                              hipStream_t stream)
{
  const float* P   = (const float*)d_in[0];
  const float* I   = (const float*)d_in[1];
  const float* Wim = (const float*)d_in[2];
  const float* bim = (const float*)d_in[3];
  const float* WL  = (const float*)d_in[4];
  const float* bL  = (const float*)d_in[5];
  const float* lng = (const float*)d_in[6];
  const float* lnb = (const float*)d_in[7];
  const float* Wf  = (const float*)d_in[8];
  const float* bf_ = (const float*)d_in[9];
  float* out = (float*)d_out;

  char* ws = (char*)d_ws;
  u16*   PT     = (u16*)(ws + 0);                      //  8 MB [4096 x 1024]
  u16*   IT     = (u16*)(ws + (size_t)8  * 1048576);   //  8 MB
  u16*   WLb    = (u16*)(ws + (size_t)16 * 1048576);   //  2 MB
  u16*   WIb    = (u16*)(ws + (size_t)18 * 1048576);   //  8 MB
  u16*   WFb    = (u16*)(ws + (size_t)26 * 1048576);   //  2 MB
  u16*   Qb     = (u16*)(ws + (size_t)28 * 1048576);   //  8 MB [1024 x 4096]
  u16*   KEYS   = (u16*)(ws + (size_t)36 * 1048576);   // 32 MB [4096 x 4096]
  float* SCORE  = (float*)(ws + (size_t)68 * 1048576); // 64 KB [4 x 4096]
  u16*   FUSED  = (u16*)(ws + (size_t)70 * 1048576);   //  8 MB [1024 x 4096]
  u16*   FUSEDT = (u16*)(ws + (size_t)78 * 1048576);   //  8 MB [4096 x 1024]

  const dim3 b256(256);

  // transposes + weight casts + SCORE zeroing, one dispatch (8208 blocks)
  prep<<<8208, b256, 0, stream>>>(P, PT, I, IT,
                                  (const float4*)Wim, (const float4*)WL,
                                  (const float4*)Wf, (ushort4*)WIb,
                                  (ushort4*)WLb, (ushort4*)WFb,
                                  (float4*)SCORE);

  // keys [4096x4096] + Q [1024x4096], both bf16, one dispatch (1280 blocks)
  gemm_keys_q<<<dim3(32, 40), b256, 0, stream>>>(WIb, IT, bim, KEYS,
                                                 WLb, PT, bL, Qb);

  // score (512 blocks, 2n/thread, atomic accumulate) -> softmax -> weightmap
  score_partial<<<dim3(8, 64), b256, 0, stream>>>(KEYS, Qb, SCORE);
  float* wmap = out + (size_t)1024 * 4096;
  softmax_h<<<16, b256, 0, stream>>>(SCORE, wmap);

  // z + residual + LayerNorm -> bf16 (8-wide), then transpose for final GEMM
  z_ln<<<1024, b256, 0, stream>>>(KEYS, Qb, wmap, lng, lnb, FUSED);
  transpose_u16<<<1024, b256, 0, stream>>>(FUSED, FUSEDT);

  // out = W_f * fused + b_f  [1024 x 4096] fp32
  gemm_bt_64<float><<<dim3(32, 16), b256, 0, stream>>>(WFb, FUSEDT, bf_, out, 1024, 4096, 1024);
}